// Round 4
// baseline (135.973 us; speedup 1.0000x reference)
//
#include <hip/hip_runtime.h>
#include <hip/hip_bf16.h>
#include <math.h>

#define B_   4
#define C_   64
#define N_   4096
#define CQK_ 16
#define L2E  1.4426950408889634f

typedef __attribute__((ext_vector_type(8))) short bf16x8;
typedef __attribute__((ext_vector_type(4))) float f32x4;

#define MFMA16(a, b, c) __builtin_amdgcn_mfma_f32_16x16x32_bf16(a, b, c, 0, 0, 0)

static __device__ inline ushort f2bf(float f) {
    __hip_bfloat16 h = __float2bfloat16(f);
    return *reinterpret_cast<ushort*>(&h);
}
static __device__ inline uint packbf(float a, float b) {
    return (uint)f2bf(a) | ((uint)f2bf(b) << 16);
}

// ---------------- QKV projection as MFMA GEMM ----------------
// OUT[96,N] = W[96,64] @ X[64,N] per batch; rows 0-15=Q(from xrgb, xL2E),
// 16-31=K, 32-95=V. Same fragment conventions as flash kernel:
// A: row=li,k=8g+r (contig) | B: col=li,k=8g+r | D: col=li,row=4g+r.
// Q,K out: [B][N][16] bf16; V out: [B][64][N] bf16.
__global__ __launch_bounds__(256) void qkv_mfma(
    const float* __restrict__ x, const float* __restrict__ xrgb,
    const float* __restrict__ Wq, const float* __restrict__ bq,
    const float* __restrict__ Wk, const float* __restrict__ bk,
    const float* __restrict__ Wv, const float* __restrict__ bv,
    ushort* __restrict__ Qo, ushort* __restrict__ Ko, ushort* __restrict__ Vo)
{
    __shared__ ushort WL[96 * 66];   // bf16 weights, pad 66 (33dw stride)
    __shared__ float  BL[96];

    const int t = threadIdx.x;
    const int b = blockIdx.y;
    const int n0 = blockIdx.x * 64;
    const int w = t >> 6, lane = t & 63, li = lane & 15, g = lane >> 4;

    for (int idx = t; idx < 96 * 64; idx += 256) {
        const int row = idx >> 6, col = idx & 63;
        float v;
        if (row < 16)      v = Wq[row * 64 + col] * L2E;   // fold log2e into Q
        else if (row < 32) v = Wk[(row - 16) * 64 + col];
        else               v = Wv[(row - 32) * 64 + col];
        WL[row * 66 + col] = f2bf(v);
    }
    if (t < 96)
        BL[t] = (t < 16) ? bq[t] * L2E : (t < 32 ? bk[t - 16] : bv[t - 32]);
    __syncthreads();

    const int n = n0 + w * 16 + li;   // wave w owns 16 pixels
    const float* xb = x    + (size_t)b * C_ * N_ + n;
    const float* rb = xrgb + (size_t)b * C_ * N_ + n;

    // B-fragments: lane (li,g) holds X[c = kk*32 + g*8 + r][n]
    bf16x8 bx[2], br[2];
    #pragma unroll
    for (int kk = 0; kk < 2; ++kk) {
        const int c0 = kk * 32 + g * 8;
        #pragma unroll
        for (int r = 0; r < 8; ++r) {
            bx[kk][r] = (short)f2bf(xb[(size_t)(c0 + r) * N_]);
            br[kk][r] = (short)f2bf(rb[(size_t)(c0 + r) * N_]);
        }
    }

    const f32x4 cz = {0.f, 0.f, 0.f, 0.f};
    #pragma unroll
    for (int ot = 0; ot < 6; ++ot) {
        const bf16x8 wa0 = *(const bf16x8*)&WL[(ot * 16 + li) * 66 + g * 8];
        const bf16x8 wa1 = *(const bf16x8*)&WL[(ot * 16 + li) * 66 + 32 + g * 8];
        f32x4 acc = cz;
        if (ot == 0) { acc = MFMA16(wa0, br[0], acc); acc = MFMA16(wa1, br[1], acc); }
        else         { acc = MFMA16(wa0, bx[0], acc); acc = MFMA16(wa1, bx[1], acc); }
        // lane (li,g): out channel o = ot*16 + g*4 + r, pixel n
        if (ot < 2) {
            uint2 pw;
            pw.x = packbf(acc[0] + BL[ot * 16 + g * 4 + 0], acc[1] + BL[ot * 16 + g * 4 + 1]);
            pw.y = packbf(acc[2] + BL[ot * 16 + g * 4 + 2], acc[3] + BL[ot * 16 + g * 4 + 3]);
            ushort* dst = (ot == 0 ? Qo : Ko) + (size_t)(b * N_ + n) * 16 + g * 4;
            *(uint2*)dst = pw;
        } else {
            #pragma unroll
            for (int r = 0; r < 4; ++r) {
                const int oc = (ot - 2) * 16 + g * 4 + r;
                Vo[(size_t)(b * C_ + oc) * N_ + n] = f2bf(acc[r] + BL[32 + oc]);
            }
        }
    }
}

// ---------------- fused flash attention, 8-way j-split ----------------
// 1024 threads = 16 waves = (jgl 0..7) x (wq 0..1). Block owns 32 queries;
// each jgl owns N/8=512 keys in 16 chunks of 32, staged in its own KL/VL
// slice. Partial (m,l,O) merged in LDS at the end. Grid 512 blocks; LDS
// 67584 -> 2 blocks/CU -> 32 waves/CU (8/SIMD).
#define SMEM_BYTES 67584
__global__ __launch_bounds__(1024, 8) void flash_attn_mfma(
    const ushort* __restrict__ Qg, const ushort* __restrict__ Kg,
    const ushort* __restrict__ Vg, const float* __restrict__ x,
    const float* __restrict__ lam, float* __restrict__ out)
{
    __shared__ __align__(16) char smem[SMEM_BYTES];
    ushort* KL = (ushort*)smem;              // [8][32][24]  12288 B
    ushort* VL = (ushort*)(smem + 12288);    // [8][64][34]  34816 B
    ushort* PL = (ushort*)(smem + 47104);    // [16][16][36] 18432 B
    // combine overlay (only after main loop's final barrier):
    float*  OC = (float*)smem;               // [2][8][64][16] 65536 B
    float*  MC = (float*)(smem + 65536);     // [2][8][16]
    float*  LC = (float*)(smem + 66560);     // [2][8][16]

    const int t    = threadIdx.x;
    const int w    = t >> 6;
    const int lane = t & 63;
    const int li   = lane & 15;
    const int g    = lane >> 4;
    const int jgl  = w >> 1;
    const int wq   = w & 1;
    const int b    = blockIdx.y;
    const int i0   = blockIdx.x * 32;
    const int iq0  = i0 + wq * 16;

    const bf16x8 fz = {0, 0, 0, 0, 0, 0, 0, 0};
    const f32x4  cz = {0.f, 0.f, 0.f, 0.f};

    // Q fragment (B operand: col=i=li, k=c=g*8+r; g>=2 zero-pads k 16->32)
    bf16x8 qf = fz;
    if (g < 2)
        qf = *(const bf16x8*)(Qg + ((size_t)(b * N_ + iq0 + li) * 16 + g * 8));

    float m_run = -1e30f, l_run = 0.f;
    f32x4 oacc[4];
    #pragma unroll
    for (int ct = 0; ct < 4; ++ct) oacc[ct] = cz;

    // staging: the jg's 128 threads (2 waves) stage its 32-key chunk
    const int tg = t & 127;
    const int kr = tg >> 2, ks = (tg & 3) * 4;      // K: 32 rows x 4 segs x 8B
    const int vr = tg >> 1, vs = (tg & 1) * 16;     // V: 64 rows x 2 segs x 32B
    const size_t jbase = (size_t)jgl * (N_ / 8);
    const ushort* ksrc = Kg + ((size_t)(b * N_) + jbase + kr) * 16 + ks;
    const ushort* vsrc = Vg + (size_t)(b * C_ + vr) * N_ + jbase + vs;
    ushort* klw = KL + (jgl * 32 + kr) * 24 + ks;
    ushort* vlw = VL + (jgl * 64 + vr) * 34 + vs;

    // prologue: stage chunk 0
    ushort4 kreg  = *(const ushort4*)(ksrc);
    uint4   vreg0 = *(const uint4*)(vsrc);
    uint4   vreg1 = *(const uint4*)(vsrc + 8);
    *(ushort4*)klw = kreg;
    *(uint4*)vlw = vreg0;
    *(uint4*)(vlw + 8) = vreg1;

    for (int jc = 0; jc < 16; ++jc) {
        __syncthreads();   // staged chunk jc visible

        if (jc + 1 < 16) {   // register prefetch of next chunk (T14)
            const size_t jn = (size_t)(jc + 1) * 32;
            kreg  = *(const ushort4*)(ksrc + jn * 16);
            vreg0 = *(const uint4*)(vsrc + jn);
            vreg1 = *(const uint4*)(vsrc + jn + 8);
        }

        // ---- energy: S^T[j][i] = sum_c K[j][c] Q[i][c]  (j = jt*16+4g+r) ----
        f32x4 st[2];
        #pragma unroll
        for (int jt = 0; jt < 2; ++jt) {
            const bf16x8 kf = *(const bf16x8*)(KL + (jgl * 32 + jt * 16 + li) * 24 + (g & 1) * 8);
            st[jt] = MFMA16(kf, qf, cz);   // k>=16 products vanish via qf zeros
        }

        // ---- online softmax (8 vals/lane), defer-rescale (T13) ----
        float m_c = fmaxf(fmaxf(fmaxf(st[0][0], st[0][1]), fmaxf(st[0][2], st[0][3])),
                          fmaxf(fmaxf(st[1][0], st[1][1]), fmaxf(st[1][2], st[1][3])));
        m_c = fmaxf(m_c, __shfl_xor(m_c, 16));
        m_c = fmaxf(m_c, __shfl_xor(m_c, 32));
        if (__any(m_c > m_run + 8.f)) {
            const float m_new = fmaxf(m_run, m_c);
            const float sc = exp2f(m_run - m_new);
            l_run *= sc;
            #pragma unroll
            for (int ct = 0; ct < 4; ++ct) {
                oacc[ct][0] *= sc; oacc[ct][1] *= sc;
                oacc[ct][2] *= sc; oacc[ct][3] *= sc;
            }
            m_run = m_new;
        }
        float psum = 0.f;
        #pragma unroll
        for (int jt = 0; jt < 2; ++jt)
            #pragma unroll
            for (int r = 0; r < 4; ++r) {
                const float p = exp2f(st[jt][r] - m_run);
                st[jt][r] = p;
                psum += p;
            }
        psum += __shfl_xor(psum, 16);
        psum += __shfl_xor(psum, 32);
        l_run += psum;

        // ---- P -> bf16 -> per-wave LDS (row i=li, col j = jt*16+g*4+r) ----
        #pragma unroll
        for (int jt = 0; jt < 2; ++jt) {
            uint2 pw;
            pw.x = packbf(st[jt][0], st[jt][1]);
            pw.y = packbf(st[jt][2], st[jt][3]);
            *(uint2*)(PL + (w * 16 + li) * 36 + jt * 16 + g * 4) = pw;
        }

        // ---- PV: O^T[c][i] += sum_j V[c][j] P^T[j][i]  (k = j = 32 exact) ----
        const bf16x8 pf = *(const bf16x8*)(PL + (w * 16 + li) * 36 + g * 8);
        #pragma unroll
        for (int ct = 0; ct < 4; ++ct) {
            const bf16x8 vf = *(const bf16x8*)(VL + (jgl * 64 + ct * 16 + li) * 34 + g * 8);
            oacc[ct] = MFMA16(vf, pf, oacc[ct]);
        }

        __syncthreads();   // all waves done reading KL/VL/PL

        if (jc + 1 < 16) {   // write prefetched chunk
            *(ushort4*)klw = kreg;
            *(uint4*)vlw = vreg0;
            *(uint4*)(vlw + 8) = vreg1;
        }
    }

    // ---- write partials into combine overlay ----
    #pragma unroll
    for (int ct = 0; ct < 4; ++ct)
        #pragma unroll
        for (int r = 0; r < 4; ++r)
            OC[((wq * 8 + jgl) * 64 + ct * 16 + g * 4 + r) * 16 + li] = oacc[ct][r];
    if (g == 0) {
        MC[(wq * 8 + jgl) * 16 + li] = m_run;
        LC[(wq * 8 + jgl) * 16 + li] = l_run;
    }
    __syncthreads();

    // ---- merge 8 j-partials; wave (wq,jgl) -> queries wq, channels jgl*8..+8
    float mp[8], lp[8];
    #pragma unroll
    for (int p = 0; p < 8; ++p) {
        mp[p] = MC[(wq * 8 + p) * 16 + li];
        lp[p] = LC[(wq * 8 + p) * 16 + li];
    }
    float ms = mp[0];
    #pragma unroll
    for (int p = 1; p < 8; ++p) ms = fmaxf(ms, mp[p]);
    float wt[8], lsum = 0.f;
    #pragma unroll
    for (int p = 0; p < 8; ++p) { wt[p] = exp2f(mp[p] - ms); lsum += wt[p] * lp[p]; }
    const float inv = lam[0] / lsum;
    const int n = i0 + wq * 16 + li;
    #pragma unroll
    for (int d = 0; d < 2; ++d) {
        const int c = jgl * 8 + g * 2 + d;
        float ov = 0.f;
        #pragma unroll
        for (int p = 0; p < 8; ++p)
            ov += wt[p] * OC[((wq * 8 + p) * 64 + c) * 16 + li];
        const size_t off = (size_t)(b * C_ + c) * N_ + n;
        out[off] = ov * inv + x[off];
    }
}

extern "C" void kernel_launch(void* const* d_in, const int* in_sizes, int n_in,
                              void* d_out, int out_size, void* d_ws, size_t ws_size,
                              hipStream_t stream)
{
    (void)in_sizes; (void)n_in; (void)out_size; (void)ws_size;
    const float* x    = (const float*)d_in[0];
    const float* xrgb = (const float*)d_in[1];
    const float* Wq   = (const float*)d_in[2];
    const float* bq   = (const float*)d_in[3];
    const float* Wk   = (const float*)d_in[4];
    const float* bk   = (const float*)d_in[5];
    const float* Wv   = (const float*)d_in[6];
    const float* bv   = (const float*)d_in[7];
    const float* lam  = (const float*)d_in[8];
    float* out = (float*)d_out;

    // workspace (bf16): Q 512KB | K 512KB | V 2MB — all fully overwritten
    ushort* Qw = (ushort*)d_ws;                       // [B][N][16]
    ushort* Kw = Qw + (size_t)B_ * N_ * CQK_;         // [B][N][16]
    ushort* Vw = Kw + (size_t)B_ * N_ * CQK_;         // [B][C][N]

    qkv_mfma<<<dim3(N_ / 64, B_), 256, 0, stream>>>(
        x, xrgb, Wq, bq, Wk, bk, Wv, bv, Qw, Kw, Vw);

    flash_attn_mfma<<<dim3(N_ / 32, B_), 1024, 0, stream>>>(
        Qw, Kw, Vw, x, lam, out);
}